// Round 2
// baseline (7905.317 us; speedup 1.0000x reference)
//
#include <hip/hip_runtime.h>
#include <hip/hip_bf16.h>

#define SEQ 2048
#define EMB 1024
#define HID 1024
#define G4  4096
#define VOC 50257
#define VPAD 50304   // 393 * 128
#define KDIM 1024

typedef short bhalf8 __attribute__((ext_vector_type(8)));
typedef float f32x4  __attribute__((ext_vector_type(4)));

typedef __attribute__((address_space(3))) void lds_void;
typedef __attribute__((address_space(1))) const void gbl_cvoid;

__device__ __forceinline__ void direct_lds16(void* lds, const void* g) {
    __builtin_amdgcn_global_load_lds((gbl_cvoid*)g, (lds_void*)lds, 16, 0, 0);
}

__device__ __forceinline__ unsigned short f2b(float f) {
    unsigned u = __float_as_uint(f);
    unsigned r = u + 0x7fffu + ((u >> 16) & 1u);
    return (unsigned short)(r >> 16);
}

// ---------------- f32 -> bf16 convert (with zero padding past n_src) ----------------
__global__ void f32_to_bf16_k(const float* __restrict__ src, unsigned short* __restrict__ dst,
                              long n_src, long n_dst) {
    long i = ((long)blockIdx.x * 256 + threadIdx.x) * 4;
    if (i >= n_dst) return;
    unsigned short o0 = 0, o1 = 0, o2 = 0, o3 = 0;
    if (i < n_src) {
        f32x4 v = *(const f32x4*)&src[i];
        o0 = f2b(v[0]); o1 = f2b(v[1]); o2 = f2b(v[2]); o3 = f2b(v[3]);
    }
    ushort4 o; o.x = o0; o.y = o1; o.z = o2; o.w = o3;
    *(ushort4*)&dst[i] = o;
}

// ---------------- embedding gather + bf16 ----------------
__global__ void embed_cvt_k(const int* __restrict__ seq, const float* __restrict__ emb,
                            unsigned short* __restrict__ xb) {
    int s = blockIdx.x;
    int k = threadIdx.x * 4;
    long row = (long)seq[s] * EMB;
    f32x4 v = *(const f32x4*)&emb[row + k];
    ushort4 o; o.x = f2b(v[0]); o.y = f2b(v[1]); o.z = f2b(v[2]); o.w = f2b(v[3]);
    *(ushort4*)&xb[(long)s * EMB + k] = o;
}

__global__ void bias_sum_k(const float* __restrict__ a, const float* __restrict__ b,
                           float* __restrict__ o) {
    int i = blockIdx.x * 256 + threadIdx.x;
    if (i < G4) o[i] = a[i] + b[i];
}

// ---------------- bf16 BT-GEMM: C[M,N] = A[M,K] @ Bt[N,K]^T + bias ----------------
// A, Bt row-major bf16 (K contiguous). 128x128 tile, BK=64, 256 threads (4 waves, 2x2 of 64x64).
// Staging via global_load_lds width=16 (wave-uniform LDS base + lane*16).
__global__ __launch_bounds__(256)
void gemm_bt_k(const unsigned short* __restrict__ A, const unsigned short* __restrict__ Bt,
               const float* __restrict__ bias, float* __restrict__ C,
               int M, int Nreal, int K, int ldc) {
    __shared__ unsigned short lA[128 * 64];
    __shared__ unsigned short lB[128 * 64];
    const int tid  = threadIdx.x;
    const int wave = tid >> 6;
    const int lane = tid & 63;
    const int m0 = blockIdx.x * 128;   // x = M tile (16 of them) -> B tile reused by consecutive blocks
    const int n0 = blockIdx.y * 128;
    const int wm = (wave >> 1) * 64;
    const int wn = (wave & 1) * 64;
    const int quad = lane >> 4, l16 = lane & 15;
    const int srow = lane >> 3;          // 0..7 row within 8-row staging slab
    const int scol = (lane & 7) * 8;     // ushort col within 64-wide row

    f32x4 acc[4][4] = {};

    for (int k0 = 0; k0 < K; k0 += 64) {
#pragma unroll
        for (int c = 0; c < 4; ++c) {
            int r0 = wave * 32 + c * 8;  // wave-uniform
            const unsigned short* ga = A  + (long)(m0 + r0 + srow) * K + k0 + scol;
            direct_lds16(&lA[r0 * 64], ga);
            const unsigned short* gb = Bt + (long)(n0 + r0 + srow) * K + k0 + scol;
            direct_lds16(&lB[r0 * 64], gb);
        }
        __syncthreads();
#pragma unroll
        for (int kk = 0; kk < 2; ++kk) {
            bhalf8 af[4], bf[4];
#pragma unroll
            for (int i = 0; i < 4; ++i) {
                af[i] = *(const bhalf8*)&lA[(wm + i * 16 + l16) * 64 + kk * 32 + quad * 8];
                bf[i] = *(const bhalf8*)&lB[(wn + i * 16 + l16) * 64 + kk * 32 + quad * 8];
            }
#pragma unroll
            for (int i = 0; i < 4; ++i)
#pragma unroll
                for (int j = 0; j < 4; ++j)
                    acc[i][j] = __builtin_amdgcn_mfma_f32_16x16x32_bf16(af[i], bf[j], acc[i][j], 0, 0, 0);
        }
        __syncthreads();
    }
    // epilogue: C/D layout col=lane&15, row=quad*4+reg (m89/m91-verified)
#pragma unroll
    for (int i = 0; i < 4; ++i) {
        int gm = m0 + wm + i * 16 + quad * 4;
#pragma unroll
        for (int j = 0; j < 4; ++j) {
            int gn = n0 + wn + j * 16 + l16;
            if (gn < Nreal) {
                float bv = bias[gn];
#pragma unroll
                for (int r = 0; r < 4; ++r)
                    C[(long)(gm + r) * ldc + gn] = acc[i][j][r] + bv;
            }
        }
    }
}

// ---------------- persistent LSTM recurrence ----------------
// 256 WGs x 256 threads. Wave = local unit (4 units/WG), lane = gate*16 + seg.
// All 4 gates of a unit live in ONE wave -> gate combine is 4 shuffles, no LDS
// round-trip, no extra barriers. h broadcast via tag-packed uint64 agent-scope
// atomics; the 4 poll loads per thread are kept IN FLIGHT TOGETHER (one
// round-trip instead of 4 serialized chains). h_lds double-buffered so the
// step loop has exactly ONE __syncthreads.
__global__ __launch_bounds__(256, 1)
void lstm_seq_k(const float* __restrict__ W_hh, const float* __restrict__ xg,
                unsigned short* __restrict__ hs_b, unsigned long long* __restrict__ hbuf) {
    const int tid  = threadIdx.x;
    const int wg   = blockIdx.x;         // 0..255
    const int wave = tid >> 6;           // local unit 0..3
    const int lane = tid & 63;
    const int gate = lane >> 4;          // 0..3 (i,f,g,o)
    const int seg  = lane & 15;          // h column segment
    const int u    = wg * 4 + wave;      // global unit
    const int grow = gate * HID + u;     // W_hh row for this lane

    __shared__ __align__(16) float h_lds[2][HID];

    f32x4 w[16];
#pragma unroll
    for (int m = 0; m < 16; ++m)
        w[m] = *(const f32x4*)&W_hh[(long)grow * HID + (m * 16 + seg) * 4];

    // unified activation: a = sc*sigmoid(sc*g) - (sc-1); sc=2 -> tanh, sc=1 -> sigmoid
    const float sc = (gate == 2) ? 2.f : 1.f;
    const float sb = sc - 1.f;

#pragma unroll
    for (int q = 0; q < 4; ++q) h_lds[0][tid + q * 256] = 0.f;
    float c = 0.f;   // persistent cell state, valid at lane==0 of each wave

    for (int t = 0; t < SEQ; ++t) {
        const int cur = t & 1;
        float xgv = (seg == 0) ? xg[(long)t * G4 + grow] : 0.f;  // issued before poll -> hidden
        if (t > 0) {
            const unsigned long long want = (unsigned long long)t;
            const unsigned long long* src = &hbuf[(1 - cur) * HID];
            const int e0 = tid, e1 = tid + 256, e2 = tid + 512, e3 = tid + 768;
            unsigned long long v0, v1, v2, v3;
            do {   // all four loads in flight together: one latency round-trip
                v0 = __hip_atomic_load(&src[e0], __ATOMIC_RELAXED, __HIP_MEMORY_SCOPE_AGENT);
                v1 = __hip_atomic_load(&src[e1], __ATOMIC_RELAXED, __HIP_MEMORY_SCOPE_AGENT);
                v2 = __hip_atomic_load(&src[e2], __ATOMIC_RELAXED, __HIP_MEMORY_SCOPE_AGENT);
                v3 = __hip_atomic_load(&src[e3], __ATOMIC_RELAXED, __HIP_MEMORY_SCOPE_AGENT);
            } while (((v0 >> 32) != want) | ((v1 >> 32) != want) |
                     ((v2 >> 32) != want) | ((v3 >> 32) != want));
            h_lds[cur][e0] = __uint_as_float((unsigned)v0);
            h_lds[cur][e1] = __uint_as_float((unsigned)v1);
            h_lds[cur][e2] = __uint_as_float((unsigned)v2);
            h_lds[cur][e3] = __uint_as_float((unsigned)v3);
        }
        __syncthreads();   // the ONLY barrier per step (fill -> read)

        // gate-row dot product: 4 partial chains to break FMA dependency
        float a0 = 0.f, a1 = 0.f, a2 = 0.f, a3 = 0.f;
        const f32x4* h4 = (const f32x4*)&h_lds[cur][0];
#pragma unroll
        for (int m = 0; m < 16; ++m) {
            f32x4 hv = h4[m * 16 + seg];
            a0 += w[m][0] * hv[0];
            a1 += w[m][1] * hv[1];
            a2 += w[m][2] * hv[2];
            a3 += w[m][3] * hv[3];
        }
        float acc = (a0 + a1) + (a2 + a3);
        acc += __shfl_xor(acc, 8);
        acc += __shfl_xor(acc, 4);
        acc += __shfl_xor(acc, 2);
        acc += __shfl_xor(acc, 1);

        float a = 0.f;
        if (seg == 0) {
            float g = acc + xgv;
            float s = 1.f / (1.f + __expf(-sc * g));
            a = sc * s - sb;
        }
        // gather the 4 gate activations of this wave's unit (lanes 0,16,32,48)
        float iv = __shfl(a, 0);
        float fv = __shfl(a, 16);
        float gv = __shfl(a, 32);
        float ov = __shfl(a, 48);
        if (lane == 0) {
            c = fv * c + iv * gv;
            float th = 2.f / (1.f + __expf(-2.f * c)) - 1.f;   // tanh(c)
            float h = ov * th;
            unsigned long long pk = ((unsigned long long)(t + 1) << 32)
                                  | (unsigned long long)__float_as_uint(h);
            __hip_atomic_store(&hbuf[cur * HID + u], pk, __ATOMIC_RELAXED, __HIP_MEMORY_SCOPE_AGENT);
            hs_b[(long)t * HID + u] = f2b(h);
        }
        // no trailing barrier: next step writes the OTHER h_lds buffer; the
        // top-of-loop barrier orders fill(t+2, same buffer) after reads(t).
    }
}

// ---------------- in-place log_softmax over rows of [SEQ][VOC] ----------------
__global__ __launch_bounds__(256)
void log_softmax_k(float* __restrict__ X) {
    const int tid = threadIdx.x;
    const long base = (long)blockIdx.x * VOC;
    float* p = X + base;
    const int head = (4 - (int)(base & 3)) & 3;
    const int n4 = (VOC - head) >> 2;
    const int tail_start = head + n4 * 4;
    f32x4* p4 = (f32x4*)(p + head);

    float m = -INFINITY, s = 0.f;
    auto upd = [&](float x) {
        float nm = fmaxf(m, x);
        s = s * __expf(m - nm) + __expf(x - nm);
        m = nm;
    };
    for (int i = tid; i < n4; i += 256) {
        f32x4 v = p4[i];
        upd(v[0]); upd(v[1]); upd(v[2]); upd(v[3]);
    }
    if (tid == 0) {
        for (int i = 0; i < head; ++i) upd(p[i]);
        for (int i = tail_start; i < VOC; ++i) upd(p[i]);
    }
#pragma unroll
    for (int o = 32; o; o >>= 1) {
        float m2 = __shfl_xor(m, o), s2 = __shfl_xor(s, o);
        float nm = fmaxf(m, m2);
        s = s * __expf(m - nm) + s2 * __expf(m2 - nm);
        m = nm;
    }
    __shared__ float sm[4], ss[4], sL;
    if ((tid & 63) == 0) { sm[tid >> 6] = m; ss[tid >> 6] = s; }
    __syncthreads();
    if (tid == 0) {
        m = sm[0]; s = ss[0];
        for (int wv = 1; wv < 4; ++wv) {
            float m2 = sm[wv], s2 = ss[wv];
            float nm = fmaxf(m, m2);
            s = s * __expf(m - nm) + s2 * __expf(m2 - nm);
            m = nm;
        }
        sL = m + __logf(s);
    }
    __syncthreads();
    const float L = sL;
    for (int i = tid; i < n4; i += 256) {
        f32x4 v = p4[i];
        v[0] -= L; v[1] -= L; v[2] -= L; v[3] -= L;
        p4[i] = v;
    }
    if (tid == 0) {
        for (int i = 0; i < head; ++i) p[i] -= L;
        for (int i = tail_start; i < VOC; ++i) p[i] -= L;
    }
}

extern "C" void kernel_launch(void* const* d_in, const int* in_sizes, int n_in,
                              void* d_out, int out_size, void* d_ws, size_t ws_size,
                              hipStream_t stream) {
    const int*   seq   = (const int*)d_in[0];
    const float* emb   = (const float*)d_in[1];
    const float* W_ih  = (const float*)d_in[2];
    const float* W_hh  = (const float*)d_in[3];
    const float* b_ih  = (const float*)d_in[4];
    const float* b_hh  = (const float*)d_in[5];
    const float* W_out = (const float*)d_in[6];
    const float* b_out = (const float*)d_in[7];
    float* out = (float*)d_out;

    size_t off = 0;
    auto carve = [&](size_t bytes) {
        void* p = (char*)d_ws + off;
        off += (bytes + 255) & ~(size_t)255;
        return p;
    };
    unsigned short* wWout = (unsigned short*)carve((size_t)VPAD * KDIM * 2);
    unsigned short* wWih  = (unsigned short*)carve((size_t)G4 * KDIM * 2);
    unsigned short* wX    = (unsigned short*)carve((size_t)SEQ * EMB * 2);
    unsigned short* wHs   = (unsigned short*)carve((size_t)SEQ * HID * 2);
    float*          wXg   = (float*)carve((size_t)SEQ * G4 * 4);
    float*          wBsum = (float*)carve((size_t)G4 * 4);
    unsigned long long* wHbuf = (unsigned long long*)carve((size_t)2 * HID * 8);

    // weight converts
    f32_to_bf16_k<<<(int)(((size_t)VPAD * KDIM / 4 + 255) / 256), 256, 0, stream>>>(
        W_out, wWout, (long)VOC * KDIM, (long)VPAD * KDIM);
    f32_to_bf16_k<<<(int)(((size_t)G4 * KDIM / 4 + 255) / 256), 256, 0, stream>>>(
        W_ih, wWih, (long)G4 * KDIM, (long)G4 * KDIM);
    embed_cvt_k<<<SEQ, 256, 0, stream>>>(seq, emb, wX);
    bias_sum_k<<<(G4 + 255) / 256, 256, 0, stream>>>(b_ih, b_hh, wBsum);

    // x_gates = x @ W_ih^T + (b_ih + b_hh)   [2048 x 4096]
    gemm_bt_k<<<dim3(SEQ / 128, G4 / 128), 256, 0, stream>>>(
        wX, wWih, wBsum, wXg, SEQ, G4, KDIM, G4);

    // sequential LSTM
    lstm_seq_k<<<256, 256, 0, stream>>>(W_hh, wXg, wHs, wHbuf);

    // logits = hs @ W_out^T + b_out  -> d_out  [2048 x 50257]
    gemm_bt_k<<<dim3(SEQ / 128, VPAD / 128), 256, 0, stream>>>(
        wHs, wWout, b_out, out, SEQ, VOC, KDIM, VOC);

    // in-place log_softmax
    log_softmax_k<<<SEQ, 256, 0, stream>>>(out);
}

// Round 3
// 7894.262 us; speedup vs baseline: 1.0014x; 1.0014x over previous
//
#include <hip/hip_runtime.h>
#include <hip/hip_bf16.h>

#define SEQ 2048
#define EMB 1024
#define HID 1024
#define G4  4096
#define VOC 50257
#define VPAD 50304   // 393 * 128
#define KDIM 1024

typedef short bhalf8 __attribute__((ext_vector_type(8)));
typedef float f32x4  __attribute__((ext_vector_type(4)));

typedef __attribute__((address_space(3))) void lds_void;
typedef __attribute__((address_space(1))) const void gbl_cvoid;

__device__ __forceinline__ void direct_lds16(void* lds, const void* g) {
    __builtin_amdgcn_global_load_lds((gbl_cvoid*)g, (lds_void*)lds, 16, 0, 0);
}

__device__ __forceinline__ unsigned short f2b(float f) {
    unsigned u = __float_as_uint(f);
    unsigned r = u + 0x7fffu + ((u >> 16) & 1u);
    return (unsigned short)(r >> 16);
}

// ---------------- f32 -> bf16 convert (with zero padding past n_src) ----------------
__global__ void f32_to_bf16_k(const float* __restrict__ src, unsigned short* __restrict__ dst,
                              long n_src, long n_dst) {
    long i = ((long)blockIdx.x * 256 + threadIdx.x) * 4;
    if (i >= n_dst) return;
    unsigned short o0 = 0, o1 = 0, o2 = 0, o3 = 0;
    if (i < n_src) {
        f32x4 v = *(const f32x4*)&src[i];
        o0 = f2b(v[0]); o1 = f2b(v[1]); o2 = f2b(v[2]); o3 = f2b(v[3]);
    }
    ushort4 o; o.x = o0; o.y = o1; o.z = o2; o.w = o3;
    *(ushort4*)&dst[i] = o;
}

// ---------------- embedding gather + bf16 ----------------
__global__ void embed_cvt_k(const int* __restrict__ seq, const float* __restrict__ emb,
                            unsigned short* __restrict__ xb) {
    int s = blockIdx.x;
    int k = threadIdx.x * 4;
    long row = (long)seq[s] * EMB;
    f32x4 v = *(const f32x4*)&emb[row + k];
    ushort4 o; o.x = f2b(v[0]); o.y = f2b(v[1]); o.z = f2b(v[2]); o.w = f2b(v[3]);
    *(ushort4*)&xb[(long)s * EMB + k] = o;
}

__global__ void bias_sum_k(const float* __restrict__ a, const float* __restrict__ b,
                           float* __restrict__ o) {
    int i = blockIdx.x * 256 + threadIdx.x;
    if (i < G4) o[i] = a[i] + b[i];
}

// ---------------- bf16 BT-GEMM: C[M,N] = A[M,K] @ Bt[N,K]^T + bias ----------------
// A, Bt row-major bf16 (K contiguous). 128x128 tile, BK=64, 256 threads (4 waves, 2x2 of 64x64).
// Staging via global_load_lds width=16 (wave-uniform LDS base + lane*16).
__global__ __launch_bounds__(256)
void gemm_bt_k(const unsigned short* __restrict__ A, const unsigned short* __restrict__ Bt,
               const float* __restrict__ bias, float* __restrict__ C,
               int M, int Nreal, int K, int ldc) {
    __shared__ unsigned short lA[128 * 64];
    __shared__ unsigned short lB[128 * 64];
    const int tid  = threadIdx.x;
    const int wave = tid >> 6;
    const int lane = tid & 63;
    const int m0 = blockIdx.x * 128;   // x = M tile (16 of them) -> B tile reused by consecutive blocks
    const int n0 = blockIdx.y * 128;
    const int wm = (wave >> 1) * 64;
    const int wn = (wave & 1) * 64;
    const int quad = lane >> 4, l16 = lane & 15;
    const int srow = lane >> 3;          // 0..7 row within 8-row staging slab
    const int scol = (lane & 7) * 8;     // ushort col within 64-wide row

    f32x4 acc[4][4] = {};

    for (int k0 = 0; k0 < K; k0 += 64) {
#pragma unroll
        for (int c = 0; c < 4; ++c) {
            int r0 = wave * 32 + c * 8;  // wave-uniform
            const unsigned short* ga = A  + (long)(m0 + r0 + srow) * K + k0 + scol;
            direct_lds16(&lA[r0 * 64], ga);
            const unsigned short* gb = Bt + (long)(n0 + r0 + srow) * K + k0 + scol;
            direct_lds16(&lB[r0 * 64], gb);
        }
        __syncthreads();
#pragma unroll
        for (int kk = 0; kk < 2; ++kk) {
            bhalf8 af[4], bf[4];
#pragma unroll
            for (int i = 0; i < 4; ++i) {
                af[i] = *(const bhalf8*)&lA[(wm + i * 16 + l16) * 64 + kk * 32 + quad * 8];
                bf[i] = *(const bhalf8*)&lB[(wn + i * 16 + l16) * 64 + kk * 32 + quad * 8];
            }
#pragma unroll
            for (int i = 0; i < 4; ++i)
#pragma unroll
                for (int j = 0; j < 4; ++j)
                    acc[i][j] = __builtin_amdgcn_mfma_f32_16x16x32_bf16(af[i], bf[j], acc[i][j], 0, 0, 0);
        }
        __syncthreads();
    }
    // epilogue: C/D layout col=lane&15, row=quad*4+reg (m89/m91-verified)
#pragma unroll
    for (int i = 0; i < 4; ++i) {
        int gm = m0 + wm + i * 16 + quad * 4;
#pragma unroll
        for (int j = 0; j < 4; ++j) {
            int gn = n0 + wn + j * 16 + l16;
            if (gn < Nreal) {
                float bv = bias[gn];
#pragma unroll
                for (int r = 0; r < 4; ++r)
                    C[(long)(gm + r) * ldc + gn] = acc[i][j][r] + bv;
            }
        }
    }
}

// ---------------- persistent LSTM recurrence ----------------
// 256 WGs x 256 threads. Wave = local unit (4 units/WG), lane = gate*16 + seg.
// All 4 gates of a unit live in ONE wave -> gate combine is 4 shuffles, no LDS
// round-trip, no extra barriers. h broadcast via tag-packed uint64 agent-scope
// atomics; the 4 poll loads per thread are kept IN FLIGHT TOGETHER (one
// round-trip instead of 4 serialized chains). h_lds double-buffered so the
// step loop has exactly ONE __syncthreads.
//
// amdgpu_waves_per_eu(1,1): grid is 256 WGs x 4 waves on 256 CUs -> exactly
// 1 wave/EU by construction. Pinning it tells regalloc it owns the full
// 512-VGPR budget, so the 64-VGPR weight cache w[16] can NEVER be spilled /
// rematerialized in-loop (a round-2 toolchain targeted the 64-VGPR occupancy
// cap, reloaded W_hh every step from L2, and doubled the kernel time).
__global__ __launch_bounds__(256) __attribute__((amdgpu_waves_per_eu(1, 1)))
void lstm_seq_k(const float* __restrict__ W_hh, const float* __restrict__ xg,
                unsigned short* __restrict__ hs_b, unsigned long long* __restrict__ hbuf) {
    const int tid  = threadIdx.x;
    const int wg   = blockIdx.x;         // 0..255
    const int wave = tid >> 6;           // local unit 0..3
    const int lane = tid & 63;
    const int gate = lane >> 4;          // 0..3 (i,f,g,o)
    const int seg  = lane & 15;          // h column segment
    const int u    = wg * 4 + wave;      // global unit
    const int grow = gate * HID + u;     // W_hh row for this lane

    __shared__ __align__(16) float h_lds[2][HID];

    f32x4 w[16];
#pragma unroll
    for (int m = 0; m < 16; ++m)
        w[m] = *(const f32x4*)&W_hh[(long)grow * HID + (m * 16 + seg) * 4];

    // unified activation: a = sc*sigmoid(sc*g) - (sc-1); sc=2 -> tanh, sc=1 -> sigmoid
    const float sc = (gate == 2) ? 2.f : 1.f;
    const float sb = sc - 1.f;

#pragma unroll
    for (int q = 0; q < 4; ++q) h_lds[0][tid + q * 256] = 0.f;
    float c = 0.f;   // persistent cell state, valid at lane==0 of each wave

    for (int t = 0; t < SEQ; ++t) {
        const int cur = t & 1;
        float xgv = (seg == 0) ? xg[(long)t * G4 + grow] : 0.f;  // issued before poll -> hidden
        if (t > 0) {
            const unsigned long long want = (unsigned long long)t;
            const unsigned long long* src = &hbuf[(1 - cur) * HID];
            const int e0 = tid, e1 = tid + 256, e2 = tid + 512, e3 = tid + 768;
            unsigned long long v0, v1, v2, v3;
            do {   // all four loads in flight together: one latency round-trip
                v0 = __hip_atomic_load(&src[e0], __ATOMIC_RELAXED, __HIP_MEMORY_SCOPE_AGENT);
                v1 = __hip_atomic_load(&src[e1], __ATOMIC_RELAXED, __HIP_MEMORY_SCOPE_AGENT);
                v2 = __hip_atomic_load(&src[e2], __ATOMIC_RELAXED, __HIP_MEMORY_SCOPE_AGENT);
                v3 = __hip_atomic_load(&src[e3], __ATOMIC_RELAXED, __HIP_MEMORY_SCOPE_AGENT);
            } while (((v0 >> 32) != want) | ((v1 >> 32) != want) |
                     ((v2 >> 32) != want) | ((v3 >> 32) != want));
            h_lds[cur][e0] = __uint_as_float((unsigned)v0);
            h_lds[cur][e1] = __uint_as_float((unsigned)v1);
            h_lds[cur][e2] = __uint_as_float((unsigned)v2);
            h_lds[cur][e3] = __uint_as_float((unsigned)v3);
        }
        __syncthreads();   // the ONLY barrier per step (fill -> read)

        // gate-row dot product: 4 partial chains to break FMA dependency
        float a0 = 0.f, a1 = 0.f, a2 = 0.f, a3 = 0.f;
        const f32x4* h4 = (const f32x4*)&h_lds[cur][0];
#pragma unroll
        for (int m = 0; m < 16; ++m) {
            f32x4 hv = h4[m * 16 + seg];
            a0 += w[m][0] * hv[0];
            a1 += w[m][1] * hv[1];
            a2 += w[m][2] * hv[2];
            a3 += w[m][3] * hv[3];
        }
        float acc = (a0 + a1) + (a2 + a3);
        acc += __shfl_xor(acc, 8);
        acc += __shfl_xor(acc, 4);
        acc += __shfl_xor(acc, 2);
        acc += __shfl_xor(acc, 1);

        float a = 0.f;
        if (seg == 0) {
            float g = acc + xgv;
            float s = 1.f / (1.f + __expf(-sc * g));
            a = sc * s - sb;
        }
        // gather the 4 gate activations of this wave's unit (lanes 0,16,32,48)
        float iv = __shfl(a, 0);
        float fv = __shfl(a, 16);
        float gv = __shfl(a, 32);
        float ov = __shfl(a, 48);
        if (lane == 0) {
            c = fv * c + iv * gv;
            float th = 2.f / (1.f + __expf(-2.f * c)) - 1.f;   // tanh(c)
            float h = ov * th;
            unsigned long long pk = ((unsigned long long)(t + 1) << 32)
                                  | (unsigned long long)__float_as_uint(h);
            __hip_atomic_store(&hbuf[cur * HID + u], pk, __ATOMIC_RELAXED, __HIP_MEMORY_SCOPE_AGENT);
            hs_b[(long)t * HID + u] = f2b(h);
        }
        // no trailing barrier: next step writes the OTHER h_lds buffer; the
        // top-of-loop barrier orders fill(t+2, same buffer) after reads(t).
    }
}

// ---------------- in-place log_softmax over rows of [SEQ][VOC] ----------------
__global__ __launch_bounds__(256)
void log_softmax_k(float* __restrict__ X) {
    const int tid = threadIdx.x;
    const long base = (long)blockIdx.x * VOC;
    float* p = X + base;
    const int head = (4 - (int)(base & 3)) & 3;
    const int n4 = (VOC - head) >> 2;
    const int tail_start = head + n4 * 4;
    f32x4* p4 = (f32x4*)(p + head);

    float m = -INFINITY, s = 0.f;
    auto upd = [&](float x) {
        float nm = fmaxf(m, x);
        s = s * __expf(m - nm) + __expf(x - nm);
        m = nm;
    };
    for (int i = tid; i < n4; i += 256) {
        f32x4 v = p4[i];
        upd(v[0]); upd(v[1]); upd(v[2]); upd(v[3]);
    }
    if (tid == 0) {
        for (int i = 0; i < head; ++i) upd(p[i]);
        for (int i = tail_start; i < VOC; ++i) upd(p[i]);
    }
#pragma unroll
    for (int o = 32; o; o >>= 1) {
        float m2 = __shfl_xor(m, o), s2 = __shfl_xor(s, o);
        float nm = fmaxf(m, m2);
        s = s * __expf(m - nm) + s2 * __expf(m2 - nm);
        m = nm;
    }
    __shared__ float sm[4], ss[4], sL;
    if ((tid & 63) == 0) { sm[tid >> 6] = m; ss[tid >> 6] = s; }
    __syncthreads();
    if (tid == 0) {
        m = sm[0]; s = ss[0];
        for (int wv = 1; wv < 4; ++wv) {
            float m2 = sm[wv], s2 = ss[wv];
            float nm = fmaxf(m, m2);
            s = s * __expf(m - nm) + s2 * __expf(m2 - nm);
            m = nm;
        }
        sL = m + __logf(s);
    }
    __syncthreads();
    const float L = sL;
    for (int i = tid; i < n4; i += 256) {
        f32x4 v = p4[i];
        v[0] -= L; v[1] -= L; v[2] -= L; v[3] -= L;
        p4[i] = v;
    }
    if (tid == 0) {
        for (int i = 0; i < head; ++i) p[i] -= L;
        for (int i = tail_start; i < VOC; ++i) p[i] -= L;
    }
}

extern "C" void kernel_launch(void* const* d_in, const int* in_sizes, int n_in,
                              void* d_out, int out_size, void* d_ws, size_t ws_size,
                              hipStream_t stream) {
    const int*   seq   = (const int*)d_in[0];
    const float* emb   = (const float*)d_in[1];
    const float* W_ih  = (const float*)d_in[2];
    const float* W_hh  = (const float*)d_in[3];
    const float* b_ih  = (const float*)d_in[4];
    const float* b_hh  = (const float*)d_in[5];
    const float* W_out = (const float*)d_in[6];
    const float* b_out = (const float*)d_in[7];
    float* out = (float*)d_out;

    size_t off = 0;
    auto carve = [&](size_t bytes) {
        void* p = (char*)d_ws + off;
        off += (bytes + 255) & ~(size_t)255;
        return p;
    };
    unsigned short* wWout = (unsigned short*)carve((size_t)VPAD * KDIM * 2);
    unsigned short* wWih  = (unsigned short*)carve((size_t)G4 * KDIM * 2);
    unsigned short* wX    = (unsigned short*)carve((size_t)SEQ * EMB * 2);
    unsigned short* wHs   = (unsigned short*)carve((size_t)SEQ * HID * 2);
    float*          wXg   = (float*)carve((size_t)SEQ * G4 * 4);
    float*          wBsum = (float*)carve((size_t)G4 * 4);
    unsigned long long* wHbuf = (unsigned long long*)carve((size_t)2 * HID * 8);

    // weight converts
    f32_to_bf16_k<<<(int)(((size_t)VPAD * KDIM / 4 + 255) / 256), 256, 0, stream>>>(
        W_out, wWout, (long)VOC * KDIM, (long)VPAD * KDIM);
    f32_to_bf16_k<<<(int)(((size_t)G4 * KDIM / 4 + 255) / 256), 256, 0, stream>>>(
        W_ih, wWih, (long)G4 * KDIM, (long)G4 * KDIM);
    embed_cvt_k<<<SEQ, 256, 0, stream>>>(seq, emb, wX);
    bias_sum_k<<<(G4 + 255) / 256, 256, 0, stream>>>(b_ih, b_hh, wBsum);

    // x_gates = x @ W_ih^T + (b_ih + b_hh)   [2048 x 4096]
    gemm_bt_k<<<dim3(SEQ / 128, G4 / 128), 256, 0, stream>>>(
        wX, wWih, wBsum, wXg, SEQ, G4, KDIM, G4);

    // sequential LSTM
    lstm_seq_k<<<256, 256, 0, stream>>>(W_hh, wXg, wHs, wHbuf);

    // logits = hs @ W_out^T + b_out  -> d_out  [2048 x 50257]
    gemm_bt_k<<<dim3(SEQ / 128, VPAD / 128), 256, 0, stream>>>(
        wHs, wWout, b_out, out, SEQ, VOC, KDIM, VOC);

    // in-place log_softmax
    log_softmax_k<<<SEQ, 256, 0, stream>>>(out);
}

// Round 4
// 7715.280 us; speedup vs baseline: 1.0246x; 1.0232x over previous
//
#include <hip/hip_runtime.h>
#include <hip/hip_bf16.h>

#define SEQ 2048
#define EMB 1024
#define HID 1024
#define G4  4096
#define VOC 50257
#define VPAD 50304   // 393 * 128
#define KDIM 1024

typedef short bhalf8 __attribute__((ext_vector_type(8)));
typedef float f32x4  __attribute__((ext_vector_type(4)));

typedef __attribute__((address_space(3))) void lds_void;
typedef __attribute__((address_space(1))) const void gbl_cvoid;

__device__ __forceinline__ void direct_lds16(void* lds, const void* g) {
    __builtin_amdgcn_global_load_lds((gbl_cvoid*)g, (lds_void*)lds, 16, 0, 0);
}

__device__ __forceinline__ unsigned short f2b(float f) {
    unsigned u = __float_as_uint(f);
    unsigned r = u + 0x7fffu + ((u >> 16) & 1u);
    return (unsigned short)(r >> 16);
}

// ---------------- f32 -> bf16 convert (with zero padding past n_src) ----------------
__global__ void f32_to_bf16_k(const float* __restrict__ src, unsigned short* __restrict__ dst,
                              long n_src, long n_dst) {
    long i = ((long)blockIdx.x * 256 + threadIdx.x) * 4;
    if (i >= n_dst) return;
    unsigned short o0 = 0, o1 = 0, o2 = 0, o3 = 0;
    if (i < n_src) {
        f32x4 v = *(const f32x4*)&src[i];
        o0 = f2b(v[0]); o1 = f2b(v[1]); o2 = f2b(v[2]); o3 = f2b(v[3]);
    }
    ushort4 o; o.x = o0; o.y = o1; o.z = o2; o.w = o3;
    *(ushort4*)&dst[i] = o;
}

// ---------------- embedding gather + bf16 ----------------
__global__ void embed_cvt_k(const int* __restrict__ seq, const float* __restrict__ emb,
                            unsigned short* __restrict__ xb) {
    int s = blockIdx.x;
    int k = threadIdx.x * 4;
    long row = (long)seq[s] * EMB;
    f32x4 v = *(const f32x4*)&emb[row + k];
    ushort4 o; o.x = f2b(v[0]); o.y = f2b(v[1]); o.z = f2b(v[2]); o.w = f2b(v[3]);
    *(ushort4*)&xb[(long)s * EMB + k] = o;
}

__global__ void bias_sum_k(const float* __restrict__ a, const float* __restrict__ b,
                           float* __restrict__ o) {
    int i = blockIdx.x * 256 + threadIdx.x;
    if (i < G4) o[i] = a[i] + b[i];
}

// ---------------- bf16 BT-GEMM: C[M,N] = A[M,K] @ Bt[N,K]^T + bias ----------------
// A, Bt row-major bf16 (K contiguous). 128x128 tile, BK=64, 256 threads (4 waves, 2x2 of 64x64).
// Staging via global_load_lds width=16 (wave-uniform LDS base + lane*16).
__global__ __launch_bounds__(256)
void gemm_bt_k(const unsigned short* __restrict__ A, const unsigned short* __restrict__ Bt,
               const float* __restrict__ bias, float* __restrict__ C,
               int M, int Nreal, int K, int ldc) {
    __shared__ unsigned short lA[128 * 64];
    __shared__ unsigned short lB[128 * 64];
    const int tid  = threadIdx.x;
    const int wave = tid >> 6;
    const int lane = tid & 63;
    const int m0 = blockIdx.x * 128;   // x = M tile (16 of them) -> B tile reused by consecutive blocks
    const int n0 = blockIdx.y * 128;
    const int wm = (wave >> 1) * 64;
    const int wn = (wave & 1) * 64;
    const int quad = lane >> 4, l16 = lane & 15;
    const int srow = lane >> 3;          // 0..7 row within 8-row staging slab
    const int scol = (lane & 7) * 8;     // ushort col within 64-wide row

    f32x4 acc[4][4] = {};

    for (int k0 = 0; k0 < K; k0 += 64) {
#pragma unroll
        for (int c = 0; c < 4; ++c) {
            int r0 = wave * 32 + c * 8;  // wave-uniform
            const unsigned short* ga = A  + (long)(m0 + r0 + srow) * K + k0 + scol;
            direct_lds16(&lA[r0 * 64], ga);
            const unsigned short* gb = Bt + (long)(n0 + r0 + srow) * K + k0 + scol;
            direct_lds16(&lB[r0 * 64], gb);
        }
        __syncthreads();
#pragma unroll
        for (int kk = 0; kk < 2; ++kk) {
            bhalf8 af[4], bf[4];
#pragma unroll
            for (int i = 0; i < 4; ++i) {
                af[i] = *(const bhalf8*)&lA[(wm + i * 16 + l16) * 64 + kk * 32 + quad * 8];
                bf[i] = *(const bhalf8*)&lB[(wn + i * 16 + l16) * 64 + kk * 32 + quad * 8];
            }
#pragma unroll
            for (int i = 0; i < 4; ++i)
#pragma unroll
                for (int j = 0; j < 4; ++j)
                    acc[i][j] = __builtin_amdgcn_mfma_f32_16x16x32_bf16(af[i], bf[j], acc[i][j], 0, 0, 0);
        }
        __syncthreads();
    }
    // epilogue: C/D layout col=lane&15, row=quad*4+reg (m89/m91-verified)
#pragma unroll
    for (int i = 0; i < 4; ++i) {
        int gm = m0 + wm + i * 16 + quad * 4;
#pragma unroll
        for (int j = 0; j < 4; ++j) {
            int gn = n0 + wn + j * 16 + l16;
            if (gn < Nreal) {
                float bv = bias[gn];
#pragma unroll
                for (int r = 0; r < 4; ++r)
                    C[(long)(gm + r) * ldc + gn] = acc[i][j][r] + bv;
            }
        }
    }
}

// ---------------- persistent LSTM recurrence ----------------
// 256 WGs x 256 threads. Wave = local unit (4 units/WG), lane = gate*16 + seg.
// All 4 gates of a unit live in ONE wave -> gate combine is 4 shuffles, no LDS
// round-trip; ONE __syncthreads per step (h_lds double-buffered).
//
// h broadcast via tag-packed uint64 stores/loads with sc0 sc1 (L1+L2 bypass,
// coherent at MALL across XCDs) — the same encoding __hip_atomic_*(AGENT)
// lowers to, but issued from ONE inline-asm block so the 4 poll loads are
// GUARANTEED to be in flight together with a single s_waitcnt (the r2/r3
// toolchain serialized the 4 atomic loads -> 4 dependent ~900cy round-trips
// -> 2x kernel time; r1's toolchain happened to batch them).
//
// amdgpu_waves_per_eu(1,1): grid is 256 WGs x 4 waves on 256 CUs -> exactly
// 1 wave/EU by construction; gives regalloc the full VGPR budget so the
// 64-VGPR weight cache w[16] stays resident under any toolchain.
__global__ __launch_bounds__(256) __attribute__((amdgpu_waves_per_eu(1, 1)))
void lstm_seq_k(const float* __restrict__ W_hh, const float* __restrict__ xg,
                unsigned short* __restrict__ hs_b, unsigned long long* __restrict__ hbuf) {
    const int tid  = threadIdx.x;
    const int wg   = blockIdx.x;         // 0..255
    const int wave = tid >> 6;           // local unit 0..3
    const int lane = tid & 63;
    const int gate = lane >> 4;          // 0..3 (i,f,g,o)
    const int seg  = lane & 15;          // h column segment
    const int u    = wg * 4 + wave;      // global unit
    const int grow = gate * HID + u;     // W_hh row for this lane

    __shared__ __align__(16) float h_lds[2][HID];

    f32x4 w[16];
#pragma unroll
    for (int m = 0; m < 16; ++m)
        w[m] = *(const f32x4*)&W_hh[(long)grow * HID + (m * 16 + seg) * 4];

    // unified activation: a = sc*sigmoid(sc*g) - (sc-1); sc=2 -> tanh, sc=1 -> sigmoid
    const float sc = (gate == 2) ? 2.f : 1.f;
    const float sb = sc - 1.f;

#pragma unroll
    for (int q = 0; q < 4; ++q) h_lds[0][tid + q * 256] = 0.f;
    float c = 0.f;   // persistent cell state, valid at lane==0 of each wave

    for (int t = 0; t < SEQ; ++t) {
        const int cur = t & 1;
        float xgv = (seg == 0) ? xg[(long)t * G4 + grow] : 0.f;  // issued before poll -> hidden
        if (t > 0) {
            const unsigned long long want = (unsigned long long)t;
            const unsigned long long* src = &hbuf[(1 - cur) * HID];
            const unsigned long long* p0 = &src[tid];
            const unsigned long long* p1 = &src[tid + 256];
            const unsigned long long* p2 = &src[tid + 512];
            const unsigned long long* p3 = &src[tid + 768];
            unsigned long long v0, v1, v2, v3;
            do {   // 4 loads issued back-to-back, ONE waitcnt: single round-trip
                asm volatile(
                    "global_load_dwordx2 %0, %4, off sc0 sc1\n\t"
                    "global_load_dwordx2 %1, %5, off sc0 sc1\n\t"
                    "global_load_dwordx2 %2, %6, off sc0 sc1\n\t"
                    "global_load_dwordx2 %3, %7, off sc0 sc1\n\t"
                    "s_waitcnt vmcnt(0)"
                    : "=&v"(v0), "=&v"(v1), "=&v"(v2), "=&v"(v3)
                    : "v"(p0), "v"(p1), "v"(p2), "v"(p3)
                    : "memory");
            } while (((v0 >> 32) != want) | ((v1 >> 32) != want) |
                     ((v2 >> 32) != want) | ((v3 >> 32) != want));
            h_lds[cur][tid]       = __uint_as_float((unsigned)v0);
            h_lds[cur][tid + 256] = __uint_as_float((unsigned)v1);
            h_lds[cur][tid + 512] = __uint_as_float((unsigned)v2);
            h_lds[cur][tid + 768] = __uint_as_float((unsigned)v3);
        }
        __syncthreads();   // the ONLY barrier per step (fill -> read)

        // gate-row dot product: 4 partial chains to break FMA dependency
        float a0 = 0.f, a1 = 0.f, a2 = 0.f, a3 = 0.f;
        const f32x4* h4 = (const f32x4*)&h_lds[cur][0];
#pragma unroll
        for (int m = 0; m < 16; ++m) {
            f32x4 hv = h4[m * 16 + seg];
            a0 += w[m][0] * hv[0];
            a1 += w[m][1] * hv[1];
            a2 += w[m][2] * hv[2];
            a3 += w[m][3] * hv[3];
        }
        float acc = (a0 + a1) + (a2 + a3);
        acc += __shfl_xor(acc, 8);
        acc += __shfl_xor(acc, 4);
        acc += __shfl_xor(acc, 2);
        acc += __shfl_xor(acc, 1);

        float a = 0.f;
        if (seg == 0) {
            float g = acc + xgv;
            float s = 1.f / (1.f + __expf(-sc * g));
            a = sc * s - sb;
        }
        // gather the 4 gate activations of this wave's unit (lanes 0,16,32,48)
        float iv = __shfl(a, 0);
        float fv = __shfl(a, 16);
        float gv = __shfl(a, 32);
        float ov = __shfl(a, 48);
        if (lane == 0) {
            c = fv * c + iv * gv;
            float th = 2.f / (1.f + __expf(-2.f * c)) - 1.f;   // tanh(c)
            float h = ov * th;
            unsigned long long pk = ((unsigned long long)(t + 1) << 32)
                                  | (unsigned long long)__float_as_uint(h);
            unsigned long long* dp = &hbuf[cur * HID + u];
            asm volatile("global_store_dwordx2 %0, %1, off sc0 sc1"
                         :: "v"(dp), "v"(pk) : "memory");
            hs_b[(long)t * HID + u] = f2b(h);
        }
        // no trailing barrier: next step writes the OTHER h_lds buffer; the
        // top-of-loop barrier orders fill(t+2, same buffer) after reads(t).
    }
}

// ---------------- in-place log_softmax over rows of [SEQ][VOC] ----------------
__global__ __launch_bounds__(256)
void log_softmax_k(float* __restrict__ X) {
    const int tid = threadIdx.x;
    const long base = (long)blockIdx.x * VOC;
    float* p = X + base;
    const int head = (4 - (int)(base & 3)) & 3;
    const int n4 = (VOC - head) >> 2;
    const int tail_start = head + n4 * 4;
    f32x4* p4 = (f32x4*)(p + head);

    float m = -INFINITY, s = 0.f;
    auto upd = [&](float x) {
        float nm = fmaxf(m, x);
        s = s * __expf(m - nm) + __expf(x - nm);
        m = nm;
    };
    for (int i = tid; i < n4; i += 256) {
        f32x4 v = p4[i];
        upd(v[0]); upd(v[1]); upd(v[2]); upd(v[3]);
    }
    if (tid == 0) {
        for (int i = 0; i < head; ++i) upd(p[i]);
        for (int i = tail_start; i < VOC; ++i) upd(p[i]);
    }
#pragma unroll
    for (int o = 32; o; o >>= 1) {
        float m2 = __shfl_xor(m, o), s2 = __shfl_xor(s, o);
        float nm = fmaxf(m, m2);
        s = s * __expf(m - nm) + s2 * __expf(m2 - nm);
        m = nm;
    }
    __shared__ float sm[4], ss[4], sL;
    if ((tid & 63) == 0) { sm[tid >> 6] = m; ss[tid >> 6] = s; }
    __syncthreads();
    if (tid == 0) {
        m = sm[0]; s = ss[0];
        for (int wv = 1; wv < 4; ++wv) {
            float m2 = sm[wv], s2 = ss[wv];
            float nm = fmaxf(m, m2);
            s = s * __expf(m - nm) + s2 * __expf(m2 - nm);
            m = nm;
        }
        sL = m + __logf(s);
    }
    __syncthreads();
    const float L = sL;
    for (int i = tid; i < n4; i += 256) {
        f32x4 v = p4[i];
        v[0] -= L; v[1] -= L; v[2] -= L; v[3] -= L;
        p4[i] = v;
    }
    if (tid == 0) {
        for (int i = 0; i < head; ++i) p[i] -= L;
        for (int i = tail_start; i < VOC; ++i) p[i] -= L;
    }
}

extern "C" void kernel_launch(void* const* d_in, const int* in_sizes, int n_in,
                              void* d_out, int out_size, void* d_ws, size_t ws_size,
                              hipStream_t stream) {
    const int*   seq   = (const int*)d_in[0];
    const float* emb   = (const float*)d_in[1];
    const float* W_ih  = (const float*)d_in[2];
    const float* W_hh  = (const float*)d_in[3];
    const float* b_ih  = (const float*)d_in[4];
    const float* b_hh  = (const float*)d_in[5];
    const float* W_out = (const float*)d_in[6];
    const float* b_out = (const float*)d_in[7];
    float* out = (float*)d_out;

    size_t off = 0;
    auto carve = [&](size_t bytes) {
        void* p = (char*)d_ws + off;
        off += (bytes + 255) & ~(size_t)255;
        return p;
    };
    unsigned short* wWout = (unsigned short*)carve((size_t)VPAD * KDIM * 2);
    unsigned short* wWih  = (unsigned short*)carve((size_t)G4 * KDIM * 2);
    unsigned short* wX    = (unsigned short*)carve((size_t)SEQ * EMB * 2);
    unsigned short* wHs   = (unsigned short*)carve((size_t)SEQ * HID * 2);
    float*          wXg   = (float*)carve((size_t)SEQ * G4 * 4);
    float*          wBsum = (float*)carve((size_t)G4 * 4);
    unsigned long long* wHbuf = (unsigned long long*)carve((size_t)2 * HID * 8);

    // weight converts
    f32_to_bf16_k<<<(int)(((size_t)VPAD * KDIM / 4 + 255) / 256), 256, 0, stream>>>(
        W_out, wWout, (long)VOC * KDIM, (long)VPAD * KDIM);
    f32_to_bf16_k<<<(int)(((size_t)G4 * KDIM / 4 + 255) / 256), 256, 0, stream>>>(
        W_ih, wWih, (long)G4 * KDIM, (long)G4 * KDIM);
    embed_cvt_k<<<SEQ, 256, 0, stream>>>(seq, emb, wX);
    bias_sum_k<<<(G4 + 255) / 256, 256, 0, stream>>>(b_ih, b_hh, wBsum);

    // x_gates = x @ W_ih^T + (b_ih + b_hh)   [2048 x 4096]
    gemm_bt_k<<<dim3(SEQ / 128, G4 / 128), 256, 0, stream>>>(
        wX, wWih, wBsum, wXg, SEQ, G4, KDIM, G4);

    // sequential LSTM
    lstm_seq_k<<<256, 256, 0, stream>>>(W_hh, wXg, wHs, wHbuf);

    // logits = hs @ W_out^T + b_out  -> d_out  [2048 x 50257]
    gemm_bt_k<<<dim3(SEQ / 128, VPAD / 128), 256, 0, stream>>>(
        wHs, wWout, b_out, out, SEQ, VOC, KDIM, VOC);

    // in-place log_softmax
    log_softmax_k<<<SEQ, 256, 0, stream>>>(out);
}

// Round 5
// 6449.526 us; speedup vs baseline: 1.2257x; 1.1963x over previous
//
#include <hip/hip_runtime.h>
#include <hip/hip_bf16.h>

#define SEQ 2048
#define EMB 1024
#define HID 1024
#define G4  4096
#define VOC 50257
#define VPAD 50304   // 393 * 128
#define KDIM 1024

typedef short bhalf8 __attribute__((ext_vector_type(8)));
typedef float f32x4  __attribute__((ext_vector_type(4)));
typedef unsigned u32x4 __attribute__((ext_vector_type(4)));

typedef __attribute__((address_space(3))) void lds_void;
typedef __attribute__((address_space(1))) const void gbl_cvoid;

__device__ __forceinline__ void direct_lds16(void* lds, const void* g) {
    __builtin_amdgcn_global_load_lds((gbl_cvoid*)g, (lds_void*)lds, 16, 0, 0);
}

__device__ __forceinline__ unsigned short f2b(float f) {
    unsigned u = __float_as_uint(f);
    unsigned r = u + 0x7fffu + ((u >> 16) & 1u);
    return (unsigned short)(r >> 16);
}

// ---------------- f32 -> bf16 convert (with zero padding past n_src) ----------------
__global__ void f32_to_bf16_k(const float* __restrict__ src, unsigned short* __restrict__ dst,
                              long n_src, long n_dst) {
    long i = ((long)blockIdx.x * 256 + threadIdx.x) * 4;
    if (i >= n_dst) return;
    unsigned short o0 = 0, o1 = 0, o2 = 0, o3 = 0;
    if (i < n_src) {
        f32x4 v = *(const f32x4*)&src[i];
        o0 = f2b(v[0]); o1 = f2b(v[1]); o2 = f2b(v[2]); o3 = f2b(v[3]);
    }
    ushort4 o; o.x = o0; o.y = o1; o.z = o2; o.w = o3;
    *(ushort4*)&dst[i] = o;
}

// ---------------- zero-fill (uint4 granularity) ----------------
__global__ void zero_k(unsigned* __restrict__ p, long n4) {
    long i = (long)blockIdx.x * 256 + threadIdx.x;
    if (i < n4) ((u32x4*)p)[i] = (u32x4){0u, 0u, 0u, 0u};
}

// ---------------- embedding gather + bf16 ----------------
__global__ void embed_cvt_k(const int* __restrict__ seq, const float* __restrict__ emb,
                            unsigned short* __restrict__ xb) {
    int s = blockIdx.x;
    int k = threadIdx.x * 4;
    long row = (long)seq[s] * EMB;
    f32x4 v = *(const f32x4*)&emb[row + k];
    ushort4 o; o.x = f2b(v[0]); o.y = f2b(v[1]); o.z = f2b(v[2]); o.w = f2b(v[3]);
    *(ushort4*)&xb[(long)s * EMB + k] = o;
}

__global__ void bias_sum_k(const float* __restrict__ a, const float* __restrict__ b,
                           float* __restrict__ o) {
    int i = blockIdx.x * 256 + threadIdx.x;
    if (i < G4) o[i] = a[i] + b[i];
}

// ---------------- bf16 BT-GEMM: C[M,N] = A[M,K] @ Bt[N,K]^T + bias ----------------
// A, Bt row-major bf16 (K contiguous). 128x128 tile, BK=64, 256 threads (4 waves, 2x2 of 64x64).
// Staging via global_load_lds width=16 (wave-uniform LDS base + lane*16).
__global__ __launch_bounds__(256)
void gemm_bt_k(const unsigned short* __restrict__ A, const unsigned short* __restrict__ Bt,
               const float* __restrict__ bias, float* __restrict__ C,
               int M, int Nreal, int K, int ldc) {
    __shared__ unsigned short lA[128 * 64];
    __shared__ unsigned short lB[128 * 64];
    const int tid  = threadIdx.x;
    const int wave = tid >> 6;
    const int lane = tid & 63;
    const int m0 = blockIdx.x * 128;   // x = M tile (16 of them) -> B tile reused by consecutive blocks
    const int n0 = blockIdx.y * 128;
    const int wm = (wave >> 1) * 64;
    const int wn = (wave & 1) * 64;
    const int quad = lane >> 4, l16 = lane & 15;
    const int srow = lane >> 3;          // 0..7 row within 8-row staging slab
    const int scol = (lane & 7) * 8;     // ushort col within 64-wide row

    f32x4 acc[4][4] = {};

    for (int k0 = 0; k0 < K; k0 += 64) {
#pragma unroll
        for (int c = 0; c < 4; ++c) {
            int r0 = wave * 32 + c * 8;  // wave-uniform
            const unsigned short* ga = A  + (long)(m0 + r0 + srow) * K + k0 + scol;
            direct_lds16(&lA[r0 * 64], ga);
            const unsigned short* gb = Bt + (long)(n0 + r0 + srow) * K + k0 + scol;
            direct_lds16(&lB[r0 * 64], gb);
        }
        __syncthreads();
#pragma unroll
        for (int kk = 0; kk < 2; ++kk) {
            bhalf8 af[4], bf[4];
#pragma unroll
            for (int i = 0; i < 4; ++i) {
                af[i] = *(const bhalf8*)&lA[(wm + i * 16 + l16) * 64 + kk * 32 + quad * 8];
                bf[i] = *(const bhalf8*)&lB[(wn + i * 16 + l16) * 64 + kk * 32 + quad * 8];
            }
#pragma unroll
            for (int i = 0; i < 4; ++i)
#pragma unroll
                for (int j = 0; j < 4; ++j)
                    acc[i][j] = __builtin_amdgcn_mfma_f32_16x16x32_bf16(af[i], bf[j], acc[i][j], 0, 0, 0);
        }
        __syncthreads();
    }
    // epilogue: C/D layout col=lane&15, row=quad*4+reg (m89/m91-verified)
#pragma unroll
    for (int i = 0; i < 4; ++i) {
        int gm = m0 + wm + i * 16 + quad * 4;
#pragma unroll
        for (int j = 0; j < 4; ++j) {
            int gn = n0 + wn + j * 16 + l16;
            if (gn < Nreal) {
                float bv = bias[gn];
#pragma unroll
                for (int r = 0; r < 4; ++r)
                    C[(long)(gm + r) * ldc + gn] = acc[i][j][r] + bv;
            }
        }
    }
}

// ---------------- persistent LSTM recurrence ----------------
// 256 WGs x 256 threads. Wave = local unit (4 units/WG), lane = gate*16 + seg.
// All 4 gates of a unit live in ONE wave -> gate combine is 4 shuffles, no LDS
// round-trip; ONE __syncthreads per step (h_lds double-buffered by parity).
//
// h broadcast transport (v2 — minimize MALL hotspot traffic):
//  * per-step FRESH region hstream[t][1024] (u32), zeroed once before launch.
//    No reuse -> no ABA -> no 32-bit tag. Validity flag = f32 mantissa LSB
//    (h stored as __float_as_uint(h)|1; rel. error 2^-24, negligible).
//  * consumer thread polls its 4 CONSECUTIVE units with ONE
//    global_load_dwordx4 sc0 sc1 (coalesced: 1 KB/wave contiguous).
//    Per-WG spin payload 8KB -> 4KB, poll instructions 4 -> 1.
//  * xg[t+1] is register-prefetched during step t so the scattered HBM read
//    can never extend the poll tail.
//
// amdgpu_waves_per_eu(1,1): grid is 256 WGs x 4 waves on 256 CUs -> exactly
// 1 wave/EU by construction; regalloc owns the full VGPR budget so the
// 64-VGPR weight cache w[16] stays resident under any toolchain.
__global__ __launch_bounds__(256) __attribute__((amdgpu_waves_per_eu(1, 1)))
void lstm_seq_k(const float* __restrict__ W_hh, const float* __restrict__ xg,
                unsigned short* __restrict__ hs_b, unsigned* __restrict__ hstream) {
    const int tid  = threadIdx.x;
    const int wg   = blockIdx.x;         // 0..255
    const int wave = tid >> 6;           // local unit 0..3
    const int lane = tid & 63;
    const int gate = lane >> 4;          // 0..3 (i,f,g,o)
    const int seg  = lane & 15;          // h column segment
    const int u    = wg * 4 + wave;      // global unit
    const int grow = gate * HID + u;     // W_hh row for this lane

    __shared__ __align__(16) float h_lds[2][HID];

    f32x4 w[16];
#pragma unroll
    for (int m = 0; m < 16; ++m)
        w[m] = *(const f32x4*)&W_hh[(long)grow * HID + (m * 16 + seg) * 4];

    // unified activation: a = sc*sigmoid(sc*g) - (sc-1); sc=2 -> tanh, sc=1 -> sigmoid
    const float sc = (gate == 2) ? 2.f : 1.f;
    const float sb = sc - 1.f;

#pragma unroll
    for (int q = 0; q < 4; ++q) h_lds[0][tid + q * 256] = 0.f;
    float c = 0.f;   // persistent cell state, valid at lane==0 of each wave

    // xg register prefetch (t=0)
    float xg_next = (seg == 0) ? xg[grow] : 0.f;

    for (int t = 0; t < SEQ; ++t) {
        const int cur = t & 1;
        const float xgv = xg_next;
        if (t > 0) {
            const unsigned* src = &hstream[(long)(t - 1) * HID + 4 * tid];
            u32x4 v;
            do {   // one coalesced 16B poll load, one waitcnt
                asm volatile(
                    "global_load_dwordx4 %0, %1, off sc0 sc1\n\t"
                    "s_waitcnt vmcnt(0)"
                    : "=&v"(v) : "v"(src) : "memory");
            } while (((v[0] & v[1] & v[2] & v[3]) & 1u) == 0u);
            ((u32x4*)&h_lds[cur][0])[tid] = v;   // bits are f32 (LSB-tagged)
        }
        __syncthreads();   // the ONLY barrier per step (fill -> read)

        // prefetch next step's xg now; completes under matvec + next poll
        if (seg == 0 && t + 1 < SEQ) xg_next = xg[(long)(t + 1) * G4 + grow];

        // gate-row dot product: 4 partial chains to break FMA dependency
        float a0 = 0.f, a1 = 0.f, a2 = 0.f, a3 = 0.f;
        const f32x4* h4 = (const f32x4*)&h_lds[cur][0];
#pragma unroll
        for (int m = 0; m < 16; ++m) {
            f32x4 hv = h4[m * 16 + seg];
            a0 += w[m][0] * hv[0];
            a1 += w[m][1] * hv[1];
            a2 += w[m][2] * hv[2];
            a3 += w[m][3] * hv[3];
        }
        float acc = (a0 + a1) + (a2 + a3);
        acc += __shfl_xor(acc, 8);
        acc += __shfl_xor(acc, 4);
        acc += __shfl_xor(acc, 2);
        acc += __shfl_xor(acc, 1);

        float a = 0.f;
        if (seg == 0) {
            float g = acc + xgv;
            float s = 1.f / (1.f + __expf(-sc * g));
            a = sc * s - sb;
        }
        // gather the 4 gate activations of this wave's unit (lanes 0,16,32,48)
        float iv = __shfl(a, 0);
        float fv = __shfl(a, 16);
        float gv = __shfl(a, 32);
        float ov = __shfl(a, 48);
        if (lane == 0) {
            c = fv * c + iv * gv;
            float th = 2.f / (1.f + __expf(-2.f * c)) - 1.f;   // tanh(c)
            float h = ov * th;
            unsigned pk = __float_as_uint(h) | 1u;   // LSB = valid flag
            unsigned* dp = &hstream[(long)t * HID + u];
            asm volatile("global_store_dword %0, %1, off sc0 sc1"
                         :: "v"(dp), "v"(pk) : "memory");
            hs_b[(long)t * HID + u] = f2b(h);
        }
        // no trailing barrier: next step writes the OTHER h_lds buffer; the
        // top-of-loop barrier orders fill(t+2, same buffer) after reads(t).
    }
}

// ---------------- in-place log_softmax over rows of [SEQ][VOC] ----------------
__global__ __launch_bounds__(256)
void log_softmax_k(float* __restrict__ X) {
    const int tid = threadIdx.x;
    const long base = (long)blockIdx.x * VOC;
    float* p = X + base;
    const int head = (4 - (int)(base & 3)) & 3;
    const int n4 = (VOC - head) >> 2;
    const int tail_start = head + n4 * 4;
    f32x4* p4 = (f32x4*)(p + head);

    float m = -INFINITY, s = 0.f;
    auto upd = [&](float x) {
        float nm = fmaxf(m, x);
        s = s * __expf(m - nm) + __expf(x - nm);
        m = nm;
    };
    for (int i = tid; i < n4; i += 256) {
        f32x4 v = p4[i];
        upd(v[0]); upd(v[1]); upd(v[2]); upd(v[3]);
    }
    if (tid == 0) {
        for (int i = 0; i < head; ++i) upd(p[i]);
        for (int i = tail_start; i < VOC; ++i) upd(p[i]);
    }
#pragma unroll
    for (int o = 32; o; o >>= 1) {
        float m2 = __shfl_xor(m, o), s2 = __shfl_xor(s, o);
        float nm = fmaxf(m, m2);
        s = s * __expf(m - nm) + s2 * __expf(m2 - nm);
        m = nm;
    }
    __shared__ float sm[4], ss[4], sL;
    if ((tid & 63) == 0) { sm[tid >> 6] = m; ss[tid >> 6] = s; }
    __syncthreads();
    if (tid == 0) {
        m = sm[0]; s = ss[0];
        for (int wv = 1; wv < 4; ++wv) {
            float m2 = sm[wv], s2 = ss[wv];
            float nm = fmaxf(m, m2);
            s = s * __expf(m - nm) + s2 * __expf(m2 - nm);
            m = nm;
        }
        sL = m + __logf(s);
    }
    __syncthreads();
    const float L = sL;
    for (int i = tid; i < n4; i += 256) {
        f32x4 v = p4[i];
        v[0] -= L; v[1] -= L; v[2] -= L; v[3] -= L;
        p4[i] = v;
    }
    if (tid == 0) {
        for (int i = 0; i < head; ++i) p[i] -= L;
        for (int i = tail_start; i < VOC; ++i) p[i] -= L;
    }
}

extern "C" void kernel_launch(void* const* d_in, const int* in_sizes, int n_in,
                              void* d_out, int out_size, void* d_ws, size_t ws_size,
                              hipStream_t stream) {
    const int*   seq   = (const int*)d_in[0];
    const float* emb   = (const float*)d_in[1];
    const float* W_ih  = (const float*)d_in[2];
    const float* W_hh  = (const float*)d_in[3];
    const float* b_ih  = (const float*)d_in[4];
    const float* b_hh  = (const float*)d_in[5];
    const float* W_out = (const float*)d_in[6];
    const float* b_out = (const float*)d_in[7];
    float* out = (float*)d_out;

    size_t off = 0;
    auto carve = [&](size_t bytes) {
        void* p = (char*)d_ws + off;
        off += (bytes + 255) & ~(size_t)255;
        return p;
    };
    unsigned short* wWout = (unsigned short*)carve((size_t)VPAD * KDIM * 2);
    unsigned short* wWih  = (unsigned short*)carve((size_t)G4 * KDIM * 2);
    unsigned short* wX    = (unsigned short*)carve((size_t)SEQ * EMB * 2);
    unsigned short* wHs   = (unsigned short*)carve((size_t)SEQ * HID * 2);
    float*          wXg   = (float*)carve((size_t)SEQ * G4 * 4);
    float*          wBsum = (float*)carve((size_t)G4 * 4);
    unsigned*       wHstream = (unsigned*)carve((size_t)SEQ * HID * 4);

    // zero the h stream (validity flags live in the data LSBs)
    zero_k<<<(int)(((size_t)SEQ * HID / 4 + 255) / 256), 256, 0, stream>>>(
        wHstream, (long)SEQ * HID / 4);

    // weight converts
    f32_to_bf16_k<<<(int)(((size_t)VPAD * KDIM / 4 + 255) / 256), 256, 0, stream>>>(
        W_out, wWout, (long)VOC * KDIM, (long)VPAD * KDIM);
    f32_to_bf16_k<<<(int)(((size_t)G4 * KDIM / 4 + 255) / 256), 256, 0, stream>>>(
        W_ih, wWih, (long)G4 * KDIM, (long)G4 * KDIM);
    embed_cvt_k<<<SEQ, 256, 0, stream>>>(seq, emb, wX);
    bias_sum_k<<<(G4 + 255) / 256, 256, 0, stream>>>(b_ih, b_hh, wBsum);

    // x_gates = x @ W_ih^T + (b_ih + b_hh)   [2048 x 4096]
    gemm_bt_k<<<dim3(SEQ / 128, G4 / 128), 256, 0, stream>>>(
        wX, wWih, wBsum, wXg, SEQ, G4, KDIM, G4);

    // sequential LSTM
    lstm_seq_k<<<256, 256, 0, stream>>>(W_hh, wXg, wHs, wHstream);

    // logits = hs @ W_out^T + b_out  -> d_out  [2048 x 50257]
    gemm_bt_k<<<dim3(SEQ / 128, VPAD / 128), 256, 0, stream>>>(
        wHs, wWout, b_out, out, SEQ, VOC, KDIM, VOC);

    // in-place log_softmax
    log_softmax_k<<<SEQ, 256, 0, stream>>>(out);
}